// Round 21
// baseline (85.626 us; speedup 1.0000x reference)
//
#include <hip/hip_runtime.h>
#include <hip/hip_bf16.h>

// out[d,l] = sum_n p[d,n] * gamma[d,n] * q[d,n]^l
// D=2048, N=16, L=4096. One block per d-row; 256 threads.
//
// R19 CALIBRATION ROUND: NT-store A/B was NULL (77.60 -> 76.79us).
// Unexplained ~27us after subtracting harness fills (44+5.5us) from the
// 77us bench number; in-kernel model says ~5-7us. This round runs the
// ENTIRE computation twice (identical values to identical addresses ->
// output unchanged). Delta vs R19 total = kernel time K. If K~27us the
// doubled kernel (~54us) enters the top-5 profile window with full
// counters; if K~7us, bench -> ~84us and the 77us baseline is
// harness-fixed overhead (roofline next round).

#define EMA_N 16
#define BLOCK 256

typedef float f32x4 __attribute__((ext_vector_type(4)));

__global__ __launch_bounds__(BLOCK) void ema_filter_kernel(
    const float* __restrict__ p,
    const float* __restrict__ q,
    const float* __restrict__ gamma,
    float* __restrict__ out,
    int L)
{
    const int d = blockIdx.x;
    const int t = threadIdx.x;

    __shared__ float  s_q[EMA_N];      // q
    __shared__ float  s_coef[EMA_N];   // p * gamma
    __shared__ float  s_qjump[EMA_N];  // q^(4*BLOCK - 4)
    __shared__ double s_logq[EMA_N];   // log2(q), f64 so l0*log2(q) is accurate

    if (t < EMA_N) {
        const size_t base = (size_t)d * EMA_N + t;
        const float qn = q[base];
        const double lg = log2((double)qn);
        s_q[t]     = qn;
        s_coef[t]  = p[base] * gamma[base];
        s_logq[t]  = lg;
        s_qjump[t] = (float)exp2((double)(4 * BLOCK - 4) * lg);
    }
    __syncthreads();

    float qv[EMA_N], qj[EMA_N];
    #pragma unroll
    for (int n = 0; n < EMA_N; ++n) {
        qv[n] = s_q[n];
        qj[n] = s_qjump[n];
    }
    const double fl0 = (double)(4 * t);
    f32x4* orow = reinterpret_cast<f32x4*>(out + (size_t)d * L);
    const int nchunk = L / (4 * BLOCK);            // 4 for L=4096

    #pragma unroll 1
    for (int pass = 0; pass < 2; ++pass) {
        float pw[EMA_N];
        #pragma unroll
        for (int n = 0; n < EMA_N; ++n) {
            // seed: (p*gamma) * q^{4t}; exp2f -> single v_exp_f32; f64
            // product keeps l0*log2(q) accurate for all l0.
            pw[n] = s_coef[n] * exp2f((float)(fl0 * s_logq[n]));
        }

        int cidx = t;
        for (int c = 0; c < nchunk; ++c) {
            float r0, r1, r2, r3;      // named scalars: guaranteed registers
            {
                float acc0 = 0.f, acc1 = 0.f;
                #pragma unroll
                for (int n = 0; n < EMA_N; n += 2) {
                    acc0 += pw[n];     pw[n]     *= qv[n];
                    acc1 += pw[n + 1]; pw[n + 1] *= qv[n + 1];
                }
                r0 = acc0 + acc1;
            }
            {
                float acc0 = 0.f, acc1 = 0.f;
                #pragma unroll
                for (int n = 0; n < EMA_N; n += 2) {
                    acc0 += pw[n];     pw[n]     *= qv[n];
                    acc1 += pw[n + 1]; pw[n + 1] *= qv[n + 1];
                }
                r1 = acc0 + acc1;
            }
            {
                float acc0 = 0.f, acc1 = 0.f;
                #pragma unroll
                for (int n = 0; n < EMA_N; n += 2) {
                    acc0 += pw[n];     pw[n]     *= qv[n];
                    acc1 += pw[n + 1]; pw[n + 1] *= qv[n + 1];
                }
                r2 = acc0 + acc1;
            }
            {
                float acc0 = 0.f, acc1 = 0.f;
                #pragma unroll
                for (int n = 0; n < EMA_N; n += 2) {
                    acc0 += pw[n];     pw[n]     *= qv[n];
                    acc1 += pw[n + 1]; pw[n + 1] *= qv[n + 1];
                }
                r3 = acc0 + acc1;
            }
            f32x4 r = { r0, r1, r2, r3 };
            orow[cidx] = r;
            cidx += BLOCK;
            if (c + 1 < nchunk) {
                #pragma unroll
                for (int n = 0; n < EMA_N; ++n) pw[n] *= qj[n];
            }
        }
        // Memory clobber: compiler must assume pass-0 stores are observed,
        // so it cannot dead-store-eliminate them against pass 1.
        asm volatile("" ::: "memory");
    }
}

extern "C" void kernel_launch(void* const* d_in, const int* in_sizes, int n_in,
                              void* d_out, int out_size, void* d_ws, size_t ws_size,
                              hipStream_t stream) {
    const float* p     = (const float*)d_in[0];   // (D, N, 1)
    const float* q     = (const float*)d_in[1];   // (D, N, 1)
    const float* gamma = (const float*)d_in[2];   // (D, N)
    // d_in[3] is `length`; L derived from out_size instead.

    const int D = in_sizes[2] / EMA_N;            // 2048
    const int L = out_size / D;                   // 4096

    ema_filter_kernel<<<D, BLOCK, 0, stream>>>(p, q, gamma, (float*)d_out, L);
}